// Round 1
// baseline (138104.504 us; speedup 1.0000x reference)
//
#include <hip/hip_runtime.h>
#include <cstddef>

#define T_STEPS 256
#define BATCH   512
#define NIN     128
#define NHID    1024

__device__ __forceinline__ float sigmoid_f(float x) {
    return 1.0f / (1.0f + __expf(-x));
}
__device__ __forceinline__ float tanh_f(float x) {
    float ax = fabsf(x);
    float t  = __expf(-2.0f * ax);
    float r  = (1.0f - t) / (1.0f + t);
    return copysignf(r, x);
}

// ---------------------------------------------------------------------------
// Input projection for one timestep: proj[b][n] = relu(x[b,t,:] @ W + bias)
// M=512 (batch), N=1024, K=128.  Tile 64x64, 256 threads, micro 4x4.
// ---------------------------------------------------------------------------
__global__ __launch_bounds__(256)
void proj_step_kernel(const float* __restrict__ x,      // [B, T, NIN]
                      const float* __restrict__ W,      // [NIN, NHID]
                      const float* __restrict__ bias,   // [NHID]
                      float* __restrict__ out,          // [B, NHID]
                      int t)
{
    __shared__ float a_sh[32][68];   // [k][row], padded
    __shared__ float b_sh[32][64];   // [k][col]

    const int tid = threadIdx.x;
    const int bm0 = blockIdx.x * 64;
    const int bn0 = blockIdx.y * 64;
    const int tx = tid & 15;         // col group (4 cols)
    const int ty = tid >> 4;         // row group (4 rows)

    const float* xbase = x + (size_t)t * NIN;   // row b at b*T*NIN

    float acc[4][4] = {};

    for (int k0 = 0; k0 < NIN; k0 += 32) {
        // stage A (transpose to [k][row])
        {
            const int k4 = tid & 7;       // float4 index in k (covers 32)
            const int r  = tid >> 3;      // 0..31
#pragma unroll
            for (int i = 0; i < 2; ++i) {
                int row = r + i * 32;
                float4 v = *(const float4*)(xbase + (size_t)(bm0 + row) * (T_STEPS * NIN) + k0 + k4 * 4);
                a_sh[k4 * 4 + 0][row] = v.x;
                a_sh[k4 * 4 + 1][row] = v.y;
                a_sh[k4 * 4 + 2][row] = v.z;
                a_sh[k4 * 4 + 3][row] = v.w;
            }
        }
        // stage B
        {
            const int c4 = tid & 15;      // 16 float4 = 64 cols
            const int kr = tid >> 4;      // 0..15
#pragma unroll
            for (int i = 0; i < 2; ++i) {
                int krow = kr + i * 16;
                float4 v = *(const float4*)(W + (size_t)(k0 + krow) * NHID + bn0 + c4 * 4);
                *(float4*)&b_sh[krow][c4 * 4] = v;
            }
        }
        __syncthreads();
#pragma unroll
        for (int k = 0; k < 32; ++k) {
            float4 av = *(const float4*)&a_sh[k][ty * 4];
            float4 bv = *(const float4*)&b_sh[k][tx * 4];
            float ar[4] = {av.x, av.y, av.z, av.w};
            float br[4] = {bv.x, bv.y, bv.z, bv.w};
#pragma unroll
            for (int r = 0; r < 4; ++r)
#pragma unroll
                for (int c = 0; c < 4; ++c)
                    acc[r][c] = fmaf(ar[r], br[c], acc[r][c]);
        }
        __syncthreads();
    }

    // epilogue: +bias, relu, store
    float4 bv = *(const float4*)&bias[bn0 + tx * 4];
    float br[4] = {bv.x, bv.y, bv.z, bv.w};
#pragma unroll
    for (int r = 0; r < 4; ++r) {
        int row = bm0 + ty * 4 + r;
        float4 o;
        o.x = fmaxf(acc[r][0] + br[0], 0.0f);
        o.y = fmaxf(acc[r][1] + br[1], 0.0f);
        o.z = fmaxf(acc[r][2] + br[2], 0.0f);
        o.w = fmaxf(acc[r][3] + br[3], 0.0f);
        *(float4*)&out[(size_t)row * NHID + bn0 + tx * 4] = o;
    }
}

// ---------------------------------------------------------------------------
// Fused LSTM step:  z = [A1, A2] @ W + bias  (M=512, K=2048, N=4096),
// then gate nonlinearities -> c_new, h_new.  TF gate order: i, j, f, o.
// Tile: 64 batch rows x 32 units (= 128 gemm cols, 4 gate strips of 32).
// Grid (8, 32) = 256 WGs.  256 threads, micro 4 rows x 4 gates x 2 units.
// BK=32, double-buffered LDS.
// ---------------------------------------------------------------------------
__global__ __launch_bounds__(256)
void lstm_step_kernel(const float* __restrict__ A1,     // [B, NHID] x-part
                      const float* __restrict__ A2,     // [B, NHID] h-part
                      const float* __restrict__ W,      // [2*NHID, 4*NHID]
                      const float* __restrict__ bias,   // [4*NHID]
                      const float* __restrict__ c_old,  // [B, NHID]
                      float* __restrict__ c_new,        // [B, NHID]
                      float* __restrict__ h_new)        // [B, NHID]
{
    __shared__ float a_sh[2][32][68];    // [buf][k][row], padded
    __shared__ float b_sh[2][32][128];   // [buf][k][gate*32 + unit]

    const int tid = threadIdx.x;
    const int bm0 = blockIdx.x * 64;
    const int u0  = blockIdx.y * 32;
    const int tx = tid & 15;             // unit pair index
    const int ty = tid >> 4;             // row quad index

    float acc[4][4][2] = {};             // [row][gate][unit]

    float4 areg[2];
    float4 breg[4];

    // global load indices (constant per thread)
    const int ak4 = tid & 7;             // k float4 (covers 32 k)
    const int ar_ = tid >> 3;            // 0..31
    const int bc4 = tid & 31;            // col float4 index 0..31
    const int bkr = tid >> 5;            // 0..7
    const int bg  = bc4 >> 3;            // gate of this float4
    const size_t bcoff = (size_t)bg * NHID + u0 + (bc4 & 7) * 4;

    auto load_global = [&](int kt) {
        const int k0 = kt * 32;
        const float* Ab = (k0 < NHID) ? (A1 + k0) : (A2 + (k0 - NHID));
        areg[0] = *(const float4*)(Ab + (size_t)(bm0 + ar_) * NHID + ak4 * 4);
        areg[1] = *(const float4*)(Ab + (size_t)(bm0 + ar_ + 32) * NHID + ak4 * 4);
#pragma unroll
        for (int i = 0; i < 4; ++i)
            breg[i] = *(const float4*)(W + (size_t)(k0 + bkr + i * 8) * (4 * NHID) + bcoff);
    };
    auto store_lds = [&](int buf) {
        a_sh[buf][ak4 * 4 + 0][ar_] = areg[0].x;
        a_sh[buf][ak4 * 4 + 1][ar_] = areg[0].y;
        a_sh[buf][ak4 * 4 + 2][ar_] = areg[0].z;
        a_sh[buf][ak4 * 4 + 3][ar_] = areg[0].w;
        a_sh[buf][ak4 * 4 + 0][ar_ + 32] = areg[1].x;
        a_sh[buf][ak4 * 4 + 1][ar_ + 32] = areg[1].y;
        a_sh[buf][ak4 * 4 + 2][ar_ + 32] = areg[1].z;
        a_sh[buf][ak4 * 4 + 3][ar_ + 32] = areg[1].w;
#pragma unroll
        for (int i = 0; i < 4; ++i)
            *(float4*)&b_sh[buf][bkr + i * 8][bc4 * 4] = breg[i];
    };

    load_global(0);
    store_lds(0);
    __syncthreads();

    const int NKT = (2 * NHID) / 32;     // 64
    for (int kt = 0; kt < NKT; ++kt) {
        const int cur = kt & 1;
        if (kt < NKT - 1) load_global(kt + 1);
#pragma unroll
        for (int k = 0; k < 32; ++k) {
            float4 av = *(const float4*)&a_sh[cur][k][ty * 4];
            float ar[4] = {av.x, av.y, av.z, av.w};
#pragma unroll
            for (int g = 0; g < 4; ++g) {
                float2 bv = *(const float2*)&b_sh[cur][k][g * 32 + tx * 2];
#pragma unroll
                for (int r = 0; r < 4; ++r) {
                    acc[r][g][0] = fmaf(ar[r], bv.x, acc[r][g][0]);
                    acc[r][g][1] = fmaf(ar[r], bv.y, acc[r][g][1]);
                }
            }
        }
        if (kt < NKT - 1) {
            __syncthreads();
            store_lds(cur ^ 1);
            __syncthreads();
        }
    }

    // epilogue: gates + state update
    const int ucol = u0 + tx * 2;
    float2 bi = *(const float2*)&bias[0 * NHID + ucol];
    float2 bj = *(const float2*)&bias[1 * NHID + ucol];
    float2 bf = *(const float2*)&bias[2 * NHID + ucol];
    float2 bo = *(const float2*)&bias[3 * NHID + ucol];
#pragma unroll
    for (int r = 0; r < 4; ++r) {
        const int row = bm0 + ty * 4 + r;
        float2 cv = *(const float2*)&c_old[(size_t)row * NHID + ucol];
        float cold[2] = {cv.x, cv.y};
        float bia[2] = {bi.x, bi.y}, bja[2] = {bj.x, bj.y};
        float bfa[2] = {bf.x, bf.y}, boa[2] = {bo.x, bo.y};
        float cn[2], hn[2];
#pragma unroll
        for (int uu = 0; uu < 2; ++uu) {
            float zi = acc[r][0][uu] + bia[uu];
            float zj = acc[r][1][uu] + bja[uu];
            float zf = acc[r][2][uu] + bfa[uu];
            float zo = acc[r][3][uu] + boa[uu];
            float c  = cold[uu] * sigmoid_f(zf + 1.0f) + sigmoid_f(zi) * tanh_f(zj);
            cn[uu] = c;
            hn[uu] = tanh_f(c) * sigmoid_f(zo);
        }
        *(float2*)&c_new[(size_t)row * NHID + ucol] = make_float2(cn[0], cn[1]);
        *(float2*)&h_new[(size_t)row * NHID + ucol] = make_float2(hn[0], hn[1]);
    }
}

// ---------------------------------------------------------------------------
extern "C" void kernel_launch(void* const* d_in, const int* in_sizes, int n_in,
                              void* d_out, int out_size, void* d_ws, size_t ws_size,
                              hipStream_t stream)
{
    const float* x   = (const float*)d_in[0];
    const float* W_h = (const float*)d_in[1];
    const float* b_h = (const float*)d_in[2];
    const float* k1  = (const float*)d_in[3];
    const float* b1  = (const float*)d_in[4];
    const float* k2  = (const float*)d_in[5];
    const float* b2  = (const float*)d_in[6];
    float* out = (float*)d_out;

    const size_t S = (size_t)BATCH * NHID;   // 524288 elements
    float* p = (float*)d_ws;
    float* c1[2]; float* h1[2]; float* c2[2]; float* h2[2]; float* proj;
    // parity-0 block first (single memset)
    c1[0] = p; p += S;  h1[0] = p; p += S;  c2[0] = p; p += S;  h2[0] = p; p += S;
    c1[1] = p; p += S;  h1[1] = p; p += S;  c2[1] = p; p += S;  h2[1] = p; p += S;
    proj  = p; p += S;

    // zero initial states (parity-0 block)
    hipMemsetAsync(d_ws, 0, 4 * S * sizeof(float), stream);

    dim3 blk(256);
    dim3 gproj(BATCH / 64, NHID / 64);   // (8, 16)
    dim3 gstep(BATCH / 64, NHID / 32);   // (8, 32)

    for (int t = 0; t < T_STEPS; ++t) {
        const int pi = t & 1;
        const int po = pi ^ 1;
        proj_step_kernel<<<gproj, blk, 0, stream>>>(x, W_h, b_h, proj, t);
        lstm_step_kernel<<<gstep, blk, 0, stream>>>(proj, h1[pi], k1, b1,
                                                    c1[pi], c1[po], h1[po]);
        float* h2out = (t == T_STEPS - 1) ? out : h2[po];
        lstm_step_kernel<<<gstep, blk, 0, stream>>>(h1[po], h2[pi], k2, b2,
                                                    c2[pi], c2[po], h2out);
    }
}

// Round 2
// 65451.379 us; speedup vs baseline: 2.1100x; 2.1100x over previous
//
#include <hip/hip_runtime.h>
#include <cstddef>
#include <cstdint>

#define T_STEPS 256
#define BATCH   512
#define NIN     128
#define NHID    1024

typedef _Float16 half8 __attribute__((ext_vector_type(8)));
typedef _Float16 half4 __attribute__((ext_vector_type(4)));
typedef float  float4v __attribute__((ext_vector_type(4)));

__device__ __forceinline__ float sigmoid_f(float x) { return 1.0f / (1.0f + __expf(-x)); }
__device__ __forceinline__ float tanh_f(float x) {
    float ax = fabsf(x);
    float t  = __expf(-2.0f * ax);
    float r  = (1.0f - t) / (1.0f + t);
    return copysignf(r, x);
}

// async global->LDS, 16B per lane; LDS dest = wave-uniform base + lane*16
__device__ __forceinline__ void gl_lds16(const void* g, void* l) {
    __builtin_amdgcn_global_load_lds(
        (const __attribute__((address_space(1))) unsigned int*)g,
        (__attribute__((address_space(3))) unsigned int*)l,
        16, 0, 0);
}

// ---------------------------------------------------------------------------
// Convert kernel [2048][4096] fp32 -> transposed fp16 hi/lo  Wt[n 4096][k 2048]
// ---------------------------------------------------------------------------
__global__ __launch_bounds__(256)
void convert_weights_kernel(const float* __restrict__ k1, const float* __restrict__ k2,
                            _Float16* __restrict__ w1h, _Float16* __restrict__ w1l,
                            _Float16* __restrict__ w2h, _Float16* __restrict__ w2l)
{
    __shared__ float t_sh[64][65];
    const float* src = blockIdx.z ? k2 : k1;
    _Float16* dh = blockIdx.z ? w2h : w1h;
    _Float16* dl = blockIdx.z ? w2l : w1l;
    const int k0 = blockIdx.x * 64;
    const int n0 = blockIdx.y * 64;
    const int rr = threadIdx.x >> 4;
    const int cc = threadIdx.x & 15;
#pragma unroll
    for (int i = 0; i < 4; ++i) {
        const int kk = rr + i * 16;
        float4 v = *(const float4*)(src + (size_t)(k0 + kk) * 4096 + n0 + cc * 4);
        t_sh[cc*4+0][kk] = v.x;
        t_sh[cc*4+1][kk] = v.y;
        t_sh[cc*4+2][kk] = v.z;
        t_sh[cc*4+3][kk] = v.w;
    }
    __syncthreads();
#pragma unroll
    for (int i = 0; i < 4; ++i) {
        const int nn = rr + i * 16;
        half4 hv, lv;
#pragma unroll
        for (int jx = 0; jx < 4; ++jx) {
            float v = t_sh[nn][cc*4+jx];
            _Float16 hi = (_Float16)v;
            hv[jx] = hi;
            lv[jx] = (_Float16)(v - (float)hi);
        }
        *(half4*)(dh + (size_t)(n0+nn)*2048 + k0 + cc*4) = hv;
        *(half4*)(dl + (size_t)(n0+nn)*2048 + k0 + cc*4) = lv;
    }
}

// ---------------------------------------------------------------------------
// Input projection, one timestep: relu(x_t @ W + b) -> fp16 hi/lo
// M32 x N64 tile, grid (16,16)=256
// ---------------------------------------------------------------------------
__global__ __launch_bounds__(256)
void proj_step_kernel(const float* __restrict__ x, const float* __restrict__ W,
                      const float* __restrict__ bias,
                      _Float16* __restrict__ ph, _Float16* __restrict__ pl, int t)
{
    __shared__ float a_sh[NIN][34];     // [k][row]
    __shared__ float b_sh[NIN][64];     // [k][col]
    const int tid = threadIdx.x;
    const int bm0 = blockIdx.x * 32;
    const int bn0 = blockIdx.y * 64;
    {
        const int r  = tid >> 3;        // 0..31
        const int k4 = tid & 7;
        const float* xr = x + (size_t)(bm0 + r) * (T_STEPS * NIN) + (size_t)t * NIN;
#pragma unroll
        for (int i = 0; i < 4; ++i) {
            const int kk = (k4 + 8*i) * 4;
            float4 v = *(const float4*)(xr + kk);
            a_sh[kk+0][r] = v.x; a_sh[kk+1][r] = v.y;
            a_sh[kk+2][r] = v.z; a_sh[kk+3][r] = v.w;
        }
    }
    {
        const int c4 = tid & 15;
        const int kr = tid >> 4;
#pragma unroll
        for (int i = 0; i < 8; ++i) {
            const int kk = kr + 16*i;
            *(float4*)&b_sh[kk][c4*4] = *(const float4*)(W + (size_t)kk * NHID + bn0 + c4*4);
        }
    }
    __syncthreads();
    const int tx = tid & 15;
    const int ty = tid >> 4;
    float acc[2][4] = {};
#pragma unroll 4
    for (int k = 0; k < NIN; ++k) {
        const float a0 = a_sh[k][ty*2+0];
        const float a1 = a_sh[k][ty*2+1];
        const float4 b = *(const float4*)&b_sh[k][tx*4];
        acc[0][0] = fmaf(a0, b.x, acc[0][0]);
        acc[0][1] = fmaf(a0, b.y, acc[0][1]);
        acc[0][2] = fmaf(a0, b.z, acc[0][2]);
        acc[0][3] = fmaf(a0, b.w, acc[0][3]);
        acc[1][0] = fmaf(a1, b.x, acc[1][0]);
        acc[1][1] = fmaf(a1, b.y, acc[1][1]);
        acc[1][2] = fmaf(a1, b.z, acc[1][2]);
        acc[1][3] = fmaf(a1, b.w, acc[1][3]);
    }
    const float4 bv = *(const float4*)&bias[bn0 + tx*4];
    const float bb[4] = {bv.x, bv.y, bv.z, bv.w};
#pragma unroll
    for (int rr2 = 0; rr2 < 2; ++rr2) {
        const int row = bm0 + ty*2 + rr2;
        half4 hv, lv;
#pragma unroll
        for (int c = 0; c < 4; ++c) {
            float vr = fmaxf(acc[rr2][c] + bb[c], 0.0f);
            _Float16 hi = (_Float16)vr;
            hv[c] = hi;
            lv[c] = (_Float16)(vr - (float)hi);
        }
        *(half4*)(ph + (size_t)row*NHID + bn0 + tx*4) = hv;
        *(half4*)(pl + (size_t)row*NHID + bn0 + tx*4) = lv;
    }
}

// ---------------------------------------------------------------------------
// Fused LSTM step via fp16-split MFMA.
// z = [A1,A2] @ W + bias  (M=512, K=2048, N=4096), gates -> c_new, h (hi/lo).
// A (activations) fp16 hi/lo; W transposed fp16 hi/lo Wt[n][k].
// Grid (4 mblk, 64 ublk); 256 thr = 4 waves = (m-half) x (k-half).
// Wave tile: M64 x 16 units x 4 gates; BK=32; LDS double-buffered 2x48KB.
// 3-product trick: Ah*Bh + Al*Bh + Ah*Bl  (fp32-class accuracy).
// ---------------------------------------------------------------------------
__global__ __launch_bounds__(256, 1)
void lstm_step_mfma(const _Float16* __restrict__ A1h, const _Float16* __restrict__ A1l,
                    const _Float16* __restrict__ A2h, const _Float16* __restrict__ A2l,
                    const _Float16* __restrict__ Wh,  const _Float16* __restrict__ Wl,
                    const float* __restrict__ bias,  const float* __restrict__ c_old,
                    float* __restrict__ c_new,
                    _Float16* __restrict__ h_hi, _Float16* __restrict__ h_lo,
                    float* __restrict__ h_f32)
{
    // buffer layout (48KB each, x2):
    //   A region 32KB: [kh 2][p 2][row 128][64B]   (row-major k-chunks, XOR-swizzled)
    //   B region 16KB at +32KB: [kh 2][p 2][nrow 64][64B]
    __shared__ __align__(16) unsigned char smem[98304];
    const int tid  = threadIdx.x;
    const int wave = tid >> 6;
    const int lane = tid & 63;
    const int mblk = blockIdx.x;      // 0..3
    const int ublk = blockIdx.y;      // 0..63
    const int mh = wave & 1;          // m-half
    const int kh = wave >> 1;         // k-half (0: input part, 1: h part)
    const int q  = lane >> 4;
    const int n  = lane & 15;

    const int srow = lane >> 2;                         // staging row-within-16
    const int kcg  = (lane & 3) ^ ((lane >> 3) & 3);    // swizzled global k-chunk

    float4v acc[4][4];
#pragma unroll
    for (int mt = 0; mt < 4; ++mt)
#pragma unroll
        for (int g = 0; g < 4; ++g)
            acc[mt][g] = (float4v){0.f, 0.f, 0.f, 0.f};

    auto stage = [&](int kt, int buf) {
        const unsigned bufoff = (unsigned)buf * 49152u;
#pragma unroll
        for (int jj = 0; jj < 12; ++jj) {
            const int j = wave + jj * 4;
            if (jj < 8) {  // A issues: j in [0,32)
                const int khs    = (j >> 4) & 1;
                const int p      = (j >> 3) & 1;
                const int rowblk = j & 7;
                const _Float16* s = khs ? (p ? A2l : A2h) : (p ? A1l : A1h);
                const _Float16* gp = s + (size_t)(mblk * 128 + rowblk * 16 + srow) * NHID
                                       + kt * 32 + kcg * 8;
                gl_lds16(gp, smem + bufoff + (unsigned)j * 1024u);
            } else {       // B issues: ib in [0,16)
                const int ib   = j - 32;
                const int khs  = (ib >> 3) & 1;
                const int p    = (ib >> 2) & 1;
                const int nblk = ib & 3;   // gate
                const _Float16* s = p ? Wl : Wh;
                const int col = nblk * 1024 + ublk * 16 + srow;
                const _Float16* gp = s + (size_t)col * 2048 + khs * 1024 + kt * 32 + kcg * 8;
                gl_lds16(gp, smem + bufoff + 32768u + (unsigned)ib * 1024u);
            }
        }
    };

    stage(0, 0);

    const int cs = q ^ ((n >> 1) & 3);   // frag-read chunk (de-swizzle)

    for (int kt = 0; kt < 32; ++kt) {
        __syncthreads();                       // drains this buf's loads (vmcnt0)
        if (kt < 31) stage(kt + 1, (kt + 1) & 1);   // prefetch overlaps compute
        const unsigned bufoff = (unsigned)(kt & 1) * 49152u;
        half8 Ah[4], Al[4];
#pragma unroll
        for (int mt = 0; mt < 4; ++mt) {
            const unsigned offh = bufoff + (unsigned)kh * 16384u
                                + (unsigned)(mh * 64 + mt * 16 + n) * 64u + (unsigned)cs * 16u;
            Ah[mt] = *(const half8*)(smem + offh);
            Al[mt] = *(const half8*)(smem + offh + 8192u);
        }
#pragma unroll
        for (int g = 0; g < 4; ++g) {
            const unsigned offb = bufoff + 32768u + (unsigned)kh * 8192u
                                + (unsigned)(g * 16 + n) * 64u + (unsigned)cs * 16u;
            half8 Bh = *(const half8*)(smem + offb);
            half8 Bl = *(const half8*)(smem + offb + 4096u);
#pragma unroll
            for (int mt = 0; mt < 4; ++mt)
                acc[mt][g] = __builtin_amdgcn_mfma_f32_16x16x32_f16(Ah[mt], Bh, acc[mt][g], 0, 0, 0);
#pragma unroll
            for (int mt = 0; mt < 4; ++mt)
                acc[mt][g] = __builtin_amdgcn_mfma_f32_16x16x32_f16(Al[mt], Bh, acc[mt][g], 0, 0, 0);
#pragma unroll
            for (int mt = 0; mt < 4; ++mt)
                acc[mt][g] = __builtin_amdgcn_mfma_f32_16x16x32_f16(Ah[mt], Bl, acc[mt][g], 0, 0, 0);
        }
    }

    // reduce k-halves: waves (kh==1) -> LDS -> waves (kh==0)
    __syncthreads();
    float* red = (float*)smem;
    if (kh == 1) {
#pragma unroll
        for (int mt = 0; mt < 4; ++mt)
#pragma unroll
            for (int g = 0; g < 4; ++g)
#pragma unroll
                for (int r = 0; r < 4; ++r)
                    red[mh * 4096 + (mt * 16 + g * 4 + r) * 64 + lane] = acc[mt][g][r];
    }
    __syncthreads();
    if (kh == 0) {
#pragma unroll
        for (int mt = 0; mt < 4; ++mt)
#pragma unroll
            for (int g = 0; g < 4; ++g)
#pragma unroll
                for (int r = 0; r < 4; ++r)
                    acc[mt][g][r] += red[mh * 4096 + (mt * 16 + g * 4 + r) * 64 + lane];

        const int unit = ublk * 16 + n;
        const float bi = bias[unit];
        const float bj = bias[NHID + unit];
        const float bf = bias[2 * NHID + unit];
        const float bo = bias[3 * NHID + unit];
#pragma unroll
        for (int mt = 0; mt < 4; ++mt) {
#pragma unroll
            for (int r = 0; r < 4; ++r) {
                const int row = mblk * 128 + mh * 64 + mt * 16 + q * 4 + r;
                const size_t idx = (size_t)row * NHID + unit;
                const float zi = acc[mt][0][r] + bi;
                const float zj = acc[mt][1][r] + bj;
                const float zf = acc[mt][2][r] + bf;
                const float zo = acc[mt][3][r] + bo;
                const float c = c_old[idx] * sigmoid_f(zf + 1.0f) + sigmoid_f(zi) * tanh_f(zj);
                const float h = tanh_f(c) * sigmoid_f(zo);
                c_new[idx] = c;
                const _Float16 hh = (_Float16)h;
                h_hi[idx] = hh;
                h_lo[idx] = (_Float16)(h - (float)hh);
                if (h_f32) h_f32[idx] = h;
            }
        }
    }
}

// ---------------------------------------------------------------------------
extern "C" void kernel_launch(void* const* d_in, const int* in_sizes, int n_in,
                              void* d_out, int out_size, void* d_ws, size_t ws_size,
                              hipStream_t stream)
{
    const float* x   = (const float*)d_in[0];
    const float* W_h = (const float*)d_in[1];
    const float* b_h = (const float*)d_in[2];
    const float* k1  = (const float*)d_in[3];
    const float* b1  = (const float*)d_in[4];
    const float* k2  = (const float*)d_in[5];
    const float* b2  = (const float*)d_in[6];
    float* out = (float*)d_out;

    const size_t MB = 1024 * 1024;
    uint8_t* w = (uint8_t*)d_ws;
    // zero block (8MB): c1p0, c2p0, h1h0, h1l0, h2h0, h2l0
    float*    c1p[2] = {(float*)(w + 0*MB),  (float*)(w + 8*MB)};
    float*    c2p[2] = {(float*)(w + 2*MB),  (float*)(w + 10*MB)};
    _Float16* h1h[2] = {(_Float16*)(w + 4*MB), (_Float16*)(w + 12*MB)};
    _Float16* h1l[2] = {(_Float16*)(w + 5*MB), (_Float16*)(w + 13*MB)};
    _Float16* h2h[2] = {(_Float16*)(w + 6*MB), (_Float16*)(w + 14*MB)};
    _Float16* h2l[2] = {(_Float16*)(w + 7*MB), (_Float16*)(w + 15*MB)};
    _Float16* projh  = (_Float16*)(w + 16*MB);
    _Float16* projl  = (_Float16*)(w + 17*MB);
    _Float16* w1h    = (_Float16*)(w + 20*MB);
    _Float16* w1l    = (_Float16*)(w + 36*MB);
    _Float16* w2h    = (_Float16*)(w + 52*MB);
    _Float16* w2l    = (_Float16*)(w + 68*MB);   // ends at 84MB

    hipMemsetAsync(d_ws, 0, 8 * MB, stream);
    convert_weights_kernel<<<dim3(32, 64, 2), 256, 0, stream>>>(k1, k2, w1h, w1l, w2h, w2l);

    for (int t = 0; t < T_STEPS; ++t) {
        const int pi = t & 1, po = pi ^ 1;
        proj_step_kernel<<<dim3(16, 16), 256, 0, stream>>>(x, W_h, b_h, projh, projl, t);
        lstm_step_mfma<<<dim3(4, 64), 256, 0, stream>>>(
            projh, projl, h1h[pi], h1l[pi], w1h, w1l, b1,
            c1p[pi], c1p[po], h1h[po], h1l[po], nullptr);
        lstm_step_mfma<<<dim3(4, 64), 256, 0, stream>>>(
            h1h[po], h1l[po], h2h[pi], h2l[pi], w2h, w2l, b2,
            c2p[pi], c2p[po], h2h[po], h2l[po],
            (t == T_STEPS - 1) ? out : nullptr);
    }
}

// Round 3
// 23797.020 us; speedup vs baseline: 5.8034x; 2.7504x over previous
//
#include <hip/hip_runtime.h>
#include <cstddef>
#include <cstdint>

#define T_STEPS 256
#define BATCH   512
#define NIN     128
#define NHID    1024

typedef _Float16 half8  __attribute__((ext_vector_type(8)));
typedef float    float4v __attribute__((ext_vector_type(4)));

__device__ __forceinline__ float sigmoid_f(float x) { return 1.0f / (1.0f + __expf(-x)); }
__device__ __forceinline__ float tanh_f(float x) {
    float ax = fabsf(x);
    float t  = __expf(-2.0f * ax);
    float r  = (1.0f - t) / (1.0f + t);
    return copysignf(r, x);
}

// ---------------------------------------------------------------------------
// Fragment layouts (16x16x32 f16 MFMA):
//   A-frag tile (16 m x 32 k) = 1KB: byte off = lane*16 + j*2,
//     value = A[m = lane&15][k = (lane>>4)*8 + j]
//   B-frag identical with n in place of m.
// Activation arrays: [p(hi/lo) 2][mtile 32][ktile 32][512 halves]  (2 MB)
// Weight arrays:     [p 2][ub 64][gate 4][ktile 64][512 halves]    (32 MB)
// c arrays: [mtile 32][utile 64][lane 64][4 floats]                (2 MB)
// ---------------------------------------------------------------------------

// Convert kernels [2048][4096] fp32 -> fragment-ordered fp16 hi/lo (run once)
__global__ __launch_bounds__(256)
void convert_weights(const float* __restrict__ k1, const float* __restrict__ k2,
                     _Float16* __restrict__ wf1, _Float16* __restrict__ wf2)
{
    __shared__ float ws2[32][17];
    const int kt    = blockIdx.x;     // 0..63
    const int ub    = blockIdx.y;     // 0..63
    const int layer = blockIdx.z;
    const float* src = layer ? k2 : k1;
    _Float16*    dst = layer ? wf2 : wf1;
    const int t = threadIdx.x;
    const size_t WPS = (size_t)64 * 4 * 64 * 512;   // p-stride (halves)
    for (int g = 0; g < 4; ++g) {
        for (int i = 0; i < 512; i += 256) {
            const int idx = t + i;
            const int kk = idx >> 4, n = idx & 15;
            ws2[kk][n] = src[(size_t)(kt * 32 + kk) * 4096 + g * 1024 + ub * 16 + n];
        }
        __syncthreads();
        const size_t base = (((size_t)ub * 4 + g) * 64 + kt) * 512;
        for (int i = 0; i < 512; i += 256) {
            const int idx = t + i;
            const int lane = idx >> 3, j = idx & 7;
            const float v = ws2[(lane >> 4) * 8 + j][lane & 15];
            const _Float16 hi = (_Float16)v;
            dst[base + idx]       = hi;
            dst[WPS + base + idx] = (_Float16)(v - (float)hi);
        }
        __syncthreads();
    }
}

// ---------------------------------------------------------------------------
// Input projection for one timestep: relu(x_t @ W + b) -> frag-layout hi/lo
// Grid 256: WG = 64 m x 32 u.
// ---------------------------------------------------------------------------
__global__ __launch_bounds__(256)
void proj_step(const float* __restrict__ x, const float* __restrict__ W,
               const float* __restrict__ bias, _Float16* __restrict__ pf, int tstep)
{
    __shared__ float xs[NIN][68];
    __shared__ float wsu[NIN][36];
    __shared__ float hl[64][36];
    const int t = threadIdx.x;
    const int id = blockIdx.x;
    const int mgrp = id & 7;
    const int wgu  = id >> 3;
    const int bm0 = mgrp * 64;
    const int u0  = wgu * 32;
    {
        const int m = t >> 2, c = t & 3;
        const float* xr = x + (size_t)(bm0 + m) * T_STEPS * NIN + (size_t)tstep * NIN;
#pragma unroll
        for (int i = 0; i < 8; ++i) {
            const int k4 = c + i * 4;
            float4v v = *(const float4v*)(xr + k4 * 4);
            xs[k4 * 4 + 0][m] = v[0];
            xs[k4 * 4 + 1][m] = v[1];
            xs[k4 * 4 + 2][m] = v[2];
            xs[k4 * 4 + 3][m] = v[3];
        }
    }
#pragma unroll
    for (int i = 0; i < 4; ++i) {
        const int idx = t + i * 256;
        const int k = idx >> 3, u4 = idx & 7;
        *(float4v*)&wsu[k][u4 * 4] = *(const float4v*)(W + (size_t)k * NHID + u0 + u4 * 4);
    }
    __syncthreads();
    const int mi = t >> 3, uq = t & 7;
    float acc[2][4] = {};
#pragma unroll 4
    for (int k = 0; k < NIN; ++k) {
        const float a0 = xs[k][mi * 2 + 0];
        const float a1 = xs[k][mi * 2 + 1];
        const float4v w = *(const float4v*)&wsu[k][uq * 4];
#pragma unroll
        for (int c = 0; c < 4; ++c) {
            acc[0][c] = fmaf(a0, w[c], acc[0][c]);
            acc[1][c] = fmaf(a1, w[c], acc[1][c]);
        }
    }
    const float4v bv = *(const float4v*)&bias[u0 + uq * 4];
#pragma unroll
    for (int r = 0; r < 2; ++r)
#pragma unroll
        for (int c = 0; c < 4; ++c)
            hl[mi * 2 + r][uq * 4 + c] = fmaxf(acc[r][c] + bv[c], 0.0f);
    __syncthreads();
    // frag-out: wave w handles m-tile w
    const int w = t >> 6, l = t & 63;
    const int mloc = w * 16 + (l & 15);
    const int q8 = (l >> 4) * 8;
    const float4v v0 = *(const float4v*)&hl[mloc][q8];
    const float4v v1 = *(const float4v*)&hl[mloc][q8 + 4];
    half8 hv, lv;
#pragma unroll
    for (int jx = 0; jx < 4; ++jx) {
        _Float16 h0 = (_Float16)v0[jx];
        _Float16 h1 = (_Float16)v1[jx];
        hv[jx]     = h0;  hv[jx + 4] = h1;
        lv[jx]     = (_Float16)(v0[jx] - (float)h0);
        lv[jx + 4] = (_Float16)(v1[jx] - (float)h1);
    }
    const size_t APS = (size_t)32 * 32 * 512;
    const size_t off = (((size_t)(mgrp * 4 + w)) * 32 + wgu) * 512 + l * 8;
    *(half8*)(pf + off)       = hv;
    *(half8*)(pf + APS + off) = lv;
}

// ---------------------------------------------------------------------------
// Fused LSTM step, LDS-free main loop.
// z = [A0k | A1k] @ W + bias (M=512, K=2048, N=4096), gates -> c_new, h-frag.
// Grid 256 (XCD-pinned), 4 waves = (nh unit-half) x (kh k-half).
// Wave: 64m x (16 units x 4 gates), 32 kt of 32k; frag loads direct from global.
// ---------------------------------------------------------------------------
__global__ __launch_bounds__(256, 1)
void lstm_step(const _Float16* __restrict__ A0, const _Float16* __restrict__ A1,
               const _Float16* __restrict__ Wf, const float* __restrict__ bias,
               const float* __restrict__ c_old, float* __restrict__ c_new,
               _Float16* __restrict__ hout, float* __restrict__ out_f32)
{
    __shared__ float red[2][4096];
    __shared__ float hl[64][36];
    const int tid = threadIdx.x;
    const int w = tid >> 6, l = tid & 63;
    const int nh = w & 1, kh = w >> 1;
    const int id  = blockIdx.x;
    const int xcd = id & 7;
    const int s   = id >> 3;
    const int mgrp = s & 7;
    const int wgu  = xcd * 4 + (s >> 3);
    const int ub   = wgu * 2 + nh;
    const int q = l >> 4, n = l & 15;

    const _Float16* Af = kh ? A1 : A0;
    const size_t APS = (size_t)32 * 32 * 512;
    const size_t WPS = (size_t)64 * 4 * 64 * 512;

    const _Float16* abase[2][4];
    const _Float16* bbase[2][4];
#pragma unroll
    for (int p = 0; p < 2; ++p)
#pragma unroll
        for (int mt = 0; mt < 4; ++mt)
            abase[p][mt] = Af + p * APS + ((size_t)(mgrp * 4 + mt) * 32) * 512 + l * 8;
#pragma unroll
    for (int p = 0; p < 2; ++p)
#pragma unroll
        for (int g = 0; g < 4; ++g)
            bbase[p][g] = Wf + p * WPS + (((size_t)ub * 4 + g) * 64 + kh * 32) * 512 + l * 8;

    half8 Ab[2][2][4], Bb[2][2][4];
    float4v acc[4][4];
#pragma unroll
    for (int mt = 0; mt < 4; ++mt)
#pragma unroll
        for (int g = 0; g < 4; ++g)
            acc[mt][g] = (float4v){0.f, 0.f, 0.f, 0.f};

    auto loadbuf = [&](int kt, int buf) {
        const int k = (kt < 31) ? kt : 31;
#pragma unroll
        for (int p = 0; p < 2; ++p)
#pragma unroll
            for (int mt = 0; mt < 4; ++mt)
                Ab[buf][p][mt] = *(const half8*)(abase[p][mt] + (size_t)k * 512);
#pragma unroll
        for (int p = 0; p < 2; ++p)
#pragma unroll
            for (int g = 0; g < 4; ++g)
                Bb[buf][p][g] = *(const half8*)(bbase[p][g] + (size_t)k * 512);
    };
    auto mstep = [&](int buf) {
#pragma unroll
        for (int g = 0; g < 4; ++g)
#pragma unroll
            for (int mt = 0; mt < 4; ++mt)
                acc[mt][g] = __builtin_amdgcn_mfma_f32_16x16x32_f16(Ab[buf][0][mt], Bb[buf][0][g], acc[mt][g], 0, 0, 0);
#pragma unroll
        for (int g = 0; g < 4; ++g)
#pragma unroll
            for (int mt = 0; mt < 4; ++mt)
                acc[mt][g] = __builtin_amdgcn_mfma_f32_16x16x32_f16(Ab[buf][1][mt], Bb[buf][0][g], acc[mt][g], 0, 0, 0);
#pragma unroll
        for (int g = 0; g < 4; ++g)
#pragma unroll
            for (int mt = 0; mt < 4; ++mt)
                acc[mt][g] = __builtin_amdgcn_mfma_f32_16x16x32_f16(Ab[buf][0][mt], Bb[buf][1][g], acc[mt][g], 0, 0, 0);
    };

    loadbuf(0, 0);
    for (int kt = 0; kt < 32; kt += 2) {
        loadbuf(kt + 1, 1);
        mstep(0);
        loadbuf(kt + 2, 0);
        mstep(1);
    }

    // k-half reduction
    __syncthreads();
    if (kh == 1) {
#pragma unroll
        for (int mt = 0; mt < 4; ++mt)
#pragma unroll
            for (int g = 0; g < 4; ++g)
#pragma unroll
                for (int r = 0; r < 4; ++r)
                    red[nh][((mt * 4 + g) * 4 + r) * 64 + l] = acc[mt][g][r];
    }
    __syncthreads();
    if (kh == 0) {
#pragma unroll
        for (int mt = 0; mt < 4; ++mt)
#pragma unroll
            for (int g = 0; g < 4; ++g)
#pragma unroll
                for (int r = 0; r < 4; ++r)
                    acc[mt][g][r] += red[nh][((mt * 4 + g) * 4 + r) * 64 + l];

        const int unit = ub * 16 + n;
        const float bi = bias[unit];
        const float bj = bias[NHID + unit];
        const float bf = bias[2 * NHID + unit];
        const float bo = bias[3 * NHID + unit];
#pragma unroll
        for (int mt = 0; mt < 4; ++mt) {
            const int mtglob = mgrp * 4 + mt;
            const size_t cbase = ((size_t)mtglob * 64 + ub) * 256 + l * 4;
            const float4v cv = *(const float4v*)(c_old + cbase);
            float4v cn;
            float hn[4];
#pragma unroll
            for (int r = 0; r < 4; ++r) {
                const float zi = acc[mt][0][r] + bi;
                const float zj = acc[mt][1][r] + bj;
                const float zf = acc[mt][2][r] + bf;
                const float zo = acc[mt][3][r] + bo;
                const float c = cv[r] * sigmoid_f(zf + 1.0f) + sigmoid_f(zi) * tanh_f(zj);
                cn[r] = c;
                hn[r] = tanh_f(c) * sigmoid_f(zo);
            }
            *(float4v*)(c_new + cbase) = cn;
#pragma unroll
            for (int r = 0; r < 4; ++r)
                hl[mt * 16 + q * 4 + r][nh * 16 + n] = hn[r];
            if (out_f32) {
#pragma unroll
                for (int r = 0; r < 4; ++r)
                    out_f32[(size_t)(mgrp * 64 + mt * 16 + q * 4 + r) * NHID + unit] = hn[r];
            }
        }
    }
    __syncthreads();
    // frag-out of new h: wave w handles m-tile w
    const int mloc = w * 16 + n;
    const int q8 = q * 8;
    const float4v v0 = *(const float4v*)&hl[mloc][q8];
    const float4v v1 = *(const float4v*)&hl[mloc][q8 + 4];
    half8 hv, lv;
#pragma unroll
    for (int jx = 0; jx < 4; ++jx) {
        _Float16 h0 = (_Float16)v0[jx];
        _Float16 h1 = (_Float16)v1[jx];
        hv[jx]     = h0;  hv[jx + 4] = h1;
        lv[jx]     = (_Float16)(v0[jx] - (float)h0);
        lv[jx + 4] = (_Float16)(v1[jx] - (float)h1);
    }
    const size_t off = (((size_t)(mgrp * 4 + w)) * 32 + wgu) * 512 + l * 8;
    *(half8*)(hout + off)       = hv;
    *(half8*)(hout + APS + off) = lv;
}

// ---------------------------------------------------------------------------
extern "C" void kernel_launch(void* const* d_in, const int* in_sizes, int n_in,
                              void* d_out, int out_size, void* d_ws, size_t ws_size,
                              hipStream_t stream)
{
    const float* x   = (const float*)d_in[0];
    const float* W_h = (const float*)d_in[1];
    const float* b_h = (const float*)d_in[2];
    const float* k1  = (const float*)d_in[3];
    const float* b1  = (const float*)d_in[4];
    const float* k2  = (const float*)d_in[5];
    const float* b2  = (const float*)d_in[6];
    float* out = (float*)d_out;

    const size_t MB = 1024 * 1024;
    uint8_t* wsb = (uint8_t*)d_ws;
    // zero block first (8 MB): c1[0], c2[0], h1f[0], h2f[0]
    float*    c1f[2] = {(float*)(wsb + 0 * MB),  (float*)(wsb + 8 * MB)};
    float*    c2f[2] = {(float*)(wsb + 2 * MB),  (float*)(wsb + 10 * MB)};
    _Float16* h1f[2] = {(_Float16*)(wsb + 4 * MB), (_Float16*)(wsb + 12 * MB)};
    _Float16* h2f[2] = {(_Float16*)(wsb + 6 * MB), (_Float16*)(wsb + 14 * MB)};
    _Float16* pf  = (_Float16*)(wsb + 16 * MB);
    _Float16* wf1 = (_Float16*)(wsb + 18 * MB);
    _Float16* wf2 = (_Float16*)(wsb + 50 * MB);   // ends at 82 MB

    hipMemsetAsync(d_ws, 0, 8 * MB, stream);
    convert_weights<<<dim3(64, 64, 2), 256, 0, stream>>>(k1, k2, wf1, wf2);

    for (int t = 0; t < T_STEPS; ++t) {
        const int pi = t & 1, po = pi ^ 1;
        proj_step<<<256, 256, 0, stream>>>(x, W_h, b_h, pf, t);
        lstm_step<<<256, 256, 0, stream>>>(pf, h1f[pi], wf1, b1,
                                           c1f[pi], c1f[po], h1f[po], nullptr);
        lstm_step<<<256, 256, 0, stream>>>(h1f[po], h2f[pi], wf2, b2,
                                           c2f[pi], c2f[po], h2f[po],
                                           (t == T_STEPS - 1) ? out : nullptr);
    }
}

// Round 5
// 17725.829 us; speedup vs baseline: 7.7911x; 1.3425x over previous
//
#include <hip/hip_runtime.h>
#include <cstddef>
#include <cstdint>

#define T_STEPS 256
#define BATCH   512
#define NIN     128
#define NHID    1024

typedef _Float16 half8  __attribute__((ext_vector_type(8)));
typedef float    float4v __attribute__((ext_vector_type(4)));

__device__ __forceinline__ float sigmoid_f(float x) { return 1.0f / (1.0f + __expf(-x)); }
__device__ __forceinline__ float tanh_f(float x) {
    float ax = fabsf(x);
    float t  = __expf(-2.0f * ax);
    float r  = (1.0f - t) / (1.0f + t);
    return copysignf(r, x);
}

// ---------------------------------------------------------------------------
// Fragment layouts (16x16x32 f16 MFMA):
//   frag tile (16 rows x 32 k) = 1KB: byte off = lane*16 + j*2,
//   value = A[r = lane&15][k = (lane>>4)*8 + j]
// Activations: [p 2][mtile 32][ktile 32][512 halves]   (2 MB)
// Weights:     [p 2][ub 64][gate 4][ktile 64][512]     (32 MB)
// c arrays:    [mtile 32][ub 64][lane 64][4 floats]    (2 MB)
// ---------------------------------------------------------------------------

__global__ __launch_bounds__(256)
void convert_weights(const float* __restrict__ k1, const float* __restrict__ k2,
                     _Float16* __restrict__ wf1, _Float16* __restrict__ wf2)
{
    __shared__ float ws2[32][17];
    const int kt    = blockIdx.x;     // 0..63
    const int ub    = blockIdx.y;     // 0..63
    const int layer = blockIdx.z;
    const float* src = layer ? k2 : k1;
    _Float16*    dst = layer ? wf2 : wf1;
    const int t = threadIdx.x;
    const size_t WPS = (size_t)64 * 4 * 64 * 512;
    for (int g = 0; g < 4; ++g) {
        for (int i = 0; i < 512; i += 256) {
            const int idx = t + i;
            const int kk = idx >> 4, n = idx & 15;
            ws2[kk][n] = src[(size_t)(kt * 32 + kk) * 4096 + g * 1024 + ub * 16 + n];
        }
        __syncthreads();
        const size_t base = (((size_t)ub * 4 + g) * 64 + kt) * 512;
        for (int i = 0; i < 512; i += 256) {
            const int idx = t + i;
            const int lane = idx >> 3, j = idx & 7;
            const float v = ws2[(lane >> 4) * 8 + j][lane & 15];
            const _Float16 hi = (_Float16)v;
            dst[base + idx]       = hi;
            dst[WPS + base + idx] = (_Float16)(v - (float)hi);
        }
        __syncthreads();
    }
}

// ---------------------------------------------------------------------------
// proj task body: relu(x_t @ W + b) -> frag hi/lo.  64 WGs, each 64m x 128u
// (4 sub-tiles of 32u).
// ---------------------------------------------------------------------------
__device__ __forceinline__ void proj_body(
    const float* __restrict__ x, const float* __restrict__ W,
    const float* __restrict__ bias, _Float16* __restrict__ pf,
    int tstep, int bid, char* smem)
{
    float (*xs)[68]  = (float(*)[68])smem;                  // [128][68]
    float (*wsu)[36] = (float(*)[36])(smem + 34816);        // [128][36]
    float (*hl)[36]  = (float(*)[36])(smem + 34816 + 18432);// [64][36]

    const int t = threadIdx.x;
    const int mgrp = bid & 7;
    const int ug0  = (bid >> 3) * 4;
    const int bm0  = mgrp * 64;
    {
        const int m = t >> 2, c = t & 3;
        const float* xr = x + (size_t)(bm0 + m) * T_STEPS * NIN + (size_t)tstep * NIN;
#pragma unroll
        for (int i = 0; i < 8; ++i) {
            const int k4 = c + i * 4;
            float4v v = *(const float4v*)(xr + k4 * 4);
            xs[k4 * 4 + 0][m] = v[0];
            xs[k4 * 4 + 1][m] = v[1];
            xs[k4 * 4 + 2][m] = v[2];
            xs[k4 * 4 + 3][m] = v[3];
        }
    }
    const size_t APS = (size_t)32 * 32 * 512;
    const int w = t >> 6, l = t & 63;
    const int mi = t >> 3, uq = t & 7;

    for (int su = 0; su < 4; ++su) {
        const int wgu = ug0 + su;
        const int u0  = wgu * 32;
        // load W tile: 128 k x 32 u  (16 KB) -- full tile (R3 bug: half-loaded)
#pragma unroll
        for (int i = 0; i < 4; ++i) {
            const int idx = t + i * 256;
            const int k = idx >> 3, u4 = idx & 7;
            *(float4v*)&wsu[k][u4 * 4] = *(const float4v*)(W + (size_t)k * NHID + u0 + u4 * 4);
        }
        __syncthreads();
        float acc[2][4] = {};
#pragma unroll 4
        for (int k = 0; k < NIN; ++k) {
            const float a0 = xs[k][mi * 2 + 0];
            const float a1 = xs[k][mi * 2 + 1];
            const float4v wv = *(const float4v*)&wsu[k][uq * 4];
#pragma unroll
            for (int c = 0; c < 4; ++c) {
                acc[0][c] = fmaf(a0, wv[c], acc[0][c]);
                acc[1][c] = fmaf(a1, wv[c], acc[1][c]);
            }
        }
        const float4v bv = *(const float4v*)&bias[u0 + uq * 4];
#pragma unroll
        for (int r = 0; r < 2; ++r)
#pragma unroll
            for (int c = 0; c < 4; ++c)
                hl[mi * 2 + r][uq * 4 + c] = fmaxf(acc[r][c] + bv[c], 0.0f);
        __syncthreads();
        // frag-out: wave w handles m-tile w
        const int mloc = w * 16 + (l & 15);
        const int q8 = (l >> 4) * 8;
        const float4v v0 = *(const float4v*)&hl[mloc][q8];
        const float4v v1 = *(const float4v*)&hl[mloc][q8 + 4];
        half8 hv, lv;
#pragma unroll
        for (int jx = 0; jx < 4; ++jx) {
            _Float16 h0 = (_Float16)v0[jx];
            _Float16 h1 = (_Float16)v1[jx];
            hv[jx]     = h0;  hv[jx + 4] = h1;
            lv[jx]     = (_Float16)(v0[jx] - (float)h0);
            lv[jx + 4] = (_Float16)(v1[jx] - (float)h1);
        }
        const size_t off = (((size_t)(mgrp * 4 + w)) * 32 + wgu) * 512 + l * 8;
        *(half8*)(pf + off)       = hv;
        *(half8*)(pf + APS + off) = lv;
        __syncthreads();
    }
}

// ---------------------------------------------------------------------------
// LSTM task body (256 threads = 4 waves = nh x kh).  Wave: 64m x 16u x 4g,
// K-half 1024 (32 kt).  Register-double-buffered direct-from-global frags.
// ---------------------------------------------------------------------------
__device__ __forceinline__ void lstm_body(
    const _Float16* __restrict__ A0, const _Float16* __restrict__ A1,
    const _Float16* __restrict__ Wf, const float* __restrict__ bias,
    const float* __restrict__ c_old, float* __restrict__ c_new,
    _Float16* __restrict__ hout, float* __restrict__ out_f32,
    int id, char* smem)
{
    float (*red)[4096] = (float(*)[4096])smem;           // [2][4096]
    float (*hl)[36]    = (float(*)[36])(smem + 32768);   // [64][36]

    const int tid = threadIdx.x;
    const int w = tid >> 6, l = tid & 63;
    const int nh = w & 1, kh = w >> 1;
    const int xcd = id & 7;
    const int s   = id >> 3;
    const int mgrp = s & 7;
    const int wgu  = xcd * 4 + (s >> 3);
    const int ub   = wgu * 2 + nh;
    const int q = l >> 4, n = l & 15;

    const _Float16* Af = kh ? A1 : A0;
    const size_t APS = (size_t)32 * 32 * 512;
    const size_t WPS = (size_t)64 * 4 * 64 * 512;

    // wave-uniform bases (SGPR) + single lane-varying byte offset
    const char* aB[2][4];
    const char* bB[2][4];
#pragma unroll
    for (int p = 0; p < 2; ++p)
#pragma unroll
        for (int mt = 0; mt < 4; ++mt)
            aB[p][mt] = (const char*)(Af + p * APS + (size_t)(mgrp * 4 + mt) * 32 * 512);
#pragma unroll
    for (int p = 0; p < 2; ++p)
#pragma unroll
        for (int g = 0; g < 4; ++g)
            bB[p][g] = (const char*)(Wf + p * WPS + (((size_t)ub * 4 + g) * 64 + kh * 32) * 512);
    const uint32_t lo16 = (uint32_t)l * 16;

    half8 Ab[2][2][4], Bb[2][2][4];
    float4v acc[4][4];
#pragma unroll
    for (int mt = 0; mt < 4; ++mt)
#pragma unroll
        for (int g = 0; g < 4; ++g)
            acc[mt][g] = (float4v){0.f, 0.f, 0.f, 0.f};

    auto loadbuf = [&](int kt, int buf) {
        const uint32_t off = lo16 + (uint32_t)((kt < 31) ? kt : 31) * 1024u;
#pragma unroll
        for (int p = 0; p < 2; ++p)
#pragma unroll
            for (int mt = 0; mt < 4; ++mt)
                Ab[buf][p][mt] = *(const half8*)(aB[p][mt] + off);
#pragma unroll
        for (int p = 0; p < 2; ++p)
#pragma unroll
            for (int g = 0; g < 4; ++g)
                Bb[buf][p][g] = *(const half8*)(bB[p][g] + off);
    };
    auto mstep = [&](int buf) {
#pragma unroll
        for (int g = 0; g < 4; ++g)
#pragma unroll
            for (int mt = 0; mt < 4; ++mt)
                acc[mt][g] = __builtin_amdgcn_mfma_f32_16x16x32_f16(Ab[buf][0][mt], Bb[buf][0][g], acc[mt][g], 0, 0, 0);
#pragma unroll
        for (int g = 0; g < 4; ++g)
#pragma unroll
            for (int mt = 0; mt < 4; ++mt)
                acc[mt][g] = __builtin_amdgcn_mfma_f32_16x16x32_f16(Ab[buf][1][mt], Bb[buf][0][g], acc[mt][g], 0, 0, 0);
#pragma unroll
        for (int g = 0; g < 4; ++g)
#pragma unroll
            for (int mt = 0; mt < 4; ++mt)
                acc[mt][g] = __builtin_amdgcn_mfma_f32_16x16x32_f16(Ab[buf][0][mt], Bb[buf][1][g], acc[mt][g], 0, 0, 0);
    };

    loadbuf(0, 0);
    for (int kt = 0; kt < 32; kt += 2) {
        loadbuf(kt + 1, 1);
        mstep(0);
        loadbuf(kt + 2, 0);
        mstep(1);
    }

    // k-half reduction
    __syncthreads();
    if (kh == 1) {
#pragma unroll
        for (int mt = 0; mt < 4; ++mt)
#pragma unroll
            for (int g = 0; g < 4; ++g)
#pragma unroll
                for (int r = 0; r < 4; ++r)
                    red[nh][((mt * 4 + g) * 4 + r) * 64 + l] = acc[mt][g][r];
    }
    __syncthreads();
    if (kh == 0) {
#pragma unroll
        for (int mt = 0; mt < 4; ++mt)
#pragma unroll
            for (int g = 0; g < 4; ++g)
#pragma unroll
                for (int r = 0; r < 4; ++r)
                    acc[mt][g][r] += red[nh][((mt * 4 + g) * 4 + r) * 64 + l];

        const int unit = ub * 16 + n;
        const float bi = bias[unit];
        const float bj = bias[NHID + unit];
        const float bf = bias[2 * NHID + unit];
        const float bo = bias[3 * NHID + unit];
#pragma unroll
        for (int mt = 0; mt < 4; ++mt) {
            const int mtglob = mgrp * 4 + mt;
            const size_t cbase = ((size_t)mtglob * 64 + ub) * 256 + l * 4;
            const float4v cv = *(const float4v*)(c_old + cbase);
            float4v cn;
            float hn[4];
#pragma unroll
            for (int r = 0; r < 4; ++r) {
                const float zi = acc[mt][0][r] + bi;
                const float zj = acc[mt][1][r] + bj;
                const float zf = acc[mt][2][r] + bf;
                const float zo = acc[mt][3][r] + bo;
                const float c = cv[r] * sigmoid_f(zf + 1.0f) + sigmoid_f(zi) * tanh_f(zj);
                cn[r] = c;
                hn[r] = tanh_f(c) * sigmoid_f(zo);
            }
            *(float4v*)(c_new + cbase) = cn;
#pragma unroll
            for (int r = 0; r < 4; ++r)
                hl[mt * 16 + q * 4 + r][nh * 16 + n] = hn[r];
            if (out_f32) {
#pragma unroll
                for (int r = 0; r < 4; ++r)
                    out_f32[(size_t)(mgrp * 64 + mt * 16 + q * 4 + r) * NHID + unit] = hn[r];
            }
        }
    }
    __syncthreads();
    // frag-out of new h: wave w handles m-tile w
    const int mloc = w * 16 + n;
    const int q8 = q * 8;
    const float4v v0 = *(const float4v*)&hl[mloc][q8];
    const float4v v1 = *(const float4v*)&hl[mloc][q8 + 4];
    half8 hv, lv;
#pragma unroll
    for (int jx = 0; jx < 4; ++jx) {
        _Float16 h0 = (_Float16)v0[jx];
        _Float16 h1 = (_Float16)v1[jx];
        hv[jx]     = h0;  hv[jx + 4] = h1;
        lv[jx]     = (_Float16)(v0[jx] - (float)h0);
        lv[jx + 4] = (_Float16)(v1[jx] - (float)h1);
    }
    const size_t off = (((size_t)(mgrp * 4 + w)) * 32 + wgu) * 512 + l * 8;
    *(half8*)(hout + off)       = hv;
    *(half8*)(hout + APS + off) = lv;
}

// ---------------------------------------------------------------------------
// One phase = proj(tp) [bids 0..63] + L1(t1) [64..319] + L2(t2) [320..575]
// ---------------------------------------------------------------------------
__global__ __launch_bounds__(256, 2)
void phase_kernel(const float* __restrict__ x, const float* __restrict__ W_h,
                  const float* __restrict__ b_h,
                  const _Float16* __restrict__ pf_in, _Float16* __restrict__ pf_out,
                  const _Float16* __restrict__ wf1, const float* __restrict__ b1,
                  const float* __restrict__ c1_in, float* __restrict__ c1_out,
                  const _Float16* __restrict__ h1_in, _Float16* __restrict__ h1_out,
                  const _Float16* __restrict__ wf2, const float* __restrict__ b2,
                  const float* __restrict__ c2_in, float* __restrict__ c2_out,
                  const _Float16* __restrict__ h2_in, _Float16* __restrict__ h2_out,
                  float* __restrict__ out_f32, int t1, int t2, int tp)
{
    __shared__ __align__(16) char smem[62464];
    const int bid = blockIdx.x;
    if (bid < 64) {
        if (tp <= 255) proj_body(x, W_h, b_h, pf_out, tp, bid, smem);
    } else if (bid < 320) {
        if (t1 <= 255) lstm_body(pf_in, h1_in, wf1, b1, c1_in, c1_out,
                                 h1_out, nullptr, bid - 64, smem);
    } else {
        if (t2 >= 0) lstm_body(h1_in, h2_in, wf2, b2, c2_in, c2_out,
                               h2_out, out_f32, bid - 320, smem);
    }
}

// ---------------------------------------------------------------------------
extern "C" void kernel_launch(void* const* d_in, const int* in_sizes, int n_in,
                              void* d_out, int out_size, void* d_ws, size_t ws_size,
                              hipStream_t stream)
{
    const float* x   = (const float*)d_in[0];
    const float* W_h = (const float*)d_in[1];
    const float* b_h = (const float*)d_in[2];
    const float* k1  = (const float*)d_in[3];
    const float* b1  = (const float*)d_in[4];
    const float* k2  = (const float*)d_in[5];
    const float* b2  = (const float*)d_in[6];
    float* out = (float*)d_out;

    const size_t MB = 1024 * 1024;
    uint8_t* wsb = (uint8_t*)d_ws;
    // Zero block (first 8 MB) = exactly the buffers read before first write:
    //   c1f[0], h1f[0]  (first L1 at phase 0, pi=0)
    //   c2f[1], h2f[1]  (first L2 at phase 1, pi=1)
    float*    c1f[2] = {(float*)(wsb + 0 * MB),    (float*)(wsb + 8 * MB)};
    _Float16* h1f[2] = {(_Float16*)(wsb + 2 * MB), (_Float16*)(wsb + 10 * MB)};
    float*    c2f[2] = {(float*)(wsb + 12 * MB),   (float*)(wsb + 4 * MB)};
    _Float16* h2f[2] = {(_Float16*)(wsb + 14 * MB),(_Float16*)(wsb + 6 * MB)};
    _Float16* pf[2]  = {(_Float16*)(wsb + 16 * MB), (_Float16*)(wsb + 18 * MB)};
    _Float16* wf1 = (_Float16*)(wsb + 20 * MB);
    _Float16* wf2 = (_Float16*)(wsb + 52 * MB);   // ends at 84 MB

    hipMemsetAsync(d_ws, 0, 8 * MB, stream);
    convert_weights<<<dim3(64, 64, 2), 256, 0, stream>>>(k1, k2, wf1, wf2);

    // pre-dispatch: proj(0) only (grid covers proj bids)
    phase_kernel<<<64, 256, 0, stream>>>(x, W_h, b_h,
        pf[0], pf[0], wf1, b1, c1f[0], c1f[1], h1f[0], h1f[1],
        wf2, b2, c2f[0], c2f[1], h2f[0], h2f[1], nullptr, 999, -1, 0);

    for (int p = 0; p <= 256; ++p) {
        const int pi = p & 1, po = pi ^ 1;
        phase_kernel<<<576, 256, 0, stream>>>(x, W_h, b_h,
            pf[pi], pf[po],
            wf1, b1, c1f[pi], c1f[po], h1f[pi], h1f[po],
            wf2, b2, c2f[pi], c2f[po], h2f[pi], h2f[po],
            (p == 256) ? out : nullptr, p, p - 1, p + 1);
    }
}

// Round 6
// 14669.643 us; speedup vs baseline: 9.4143x; 1.2083x over previous
//
#include <hip/hip_runtime.h>
#include <cstddef>
#include <cstdint>

#define T_STEPS 256
#define BATCH   512
#define NIN     128
#define NHID    1024

typedef _Float16 half8  __attribute__((ext_vector_type(8)));
typedef float    float4v __attribute__((ext_vector_type(4)));

__device__ __forceinline__ float sigmoid_f(float x) { return 1.0f / (1.0f + __expf(-x)); }
__device__ __forceinline__ float tanh_f(float x) {
    float ax = fabsf(x);
    float t  = __expf(-2.0f * ax);
    float r  = (1.0f - t) / (1.0f + t);
    return copysignf(r, x);
}

// ---------------------------------------------------------------------------
// Fragment layouts (16x16x32 f16 MFMA):
//   frag tile (16 rows x 32 k) = 1KB: halves index lane*8 + j,
//   value = A[r = lane&15][k = (lane>>4)*8 + j]
// Activations: [p 2][mtile 32][ktile 32][512 halves]   (2 MB)
// Weights:     [p 2][ub 64][gate 4][ktile 64][512]     (32 MB)
// c arrays:    [mtile 32][ub 64][lane 64][4 floats]    (2 MB)
// ---------------------------------------------------------------------------

__global__ __launch_bounds__(256)
void convert_weights(const float* __restrict__ k1, const float* __restrict__ k2,
                     _Float16* __restrict__ wf1, _Float16* __restrict__ wf2)
{
    __shared__ float ws2[32][17];
    const int kt    = blockIdx.x;     // 0..63
    const int ub    = blockIdx.y;     // 0..63
    const int layer = blockIdx.z;
    const float* src = layer ? k2 : k1;
    _Float16*    dst = layer ? wf2 : wf1;
    const int t = threadIdx.x;
    const size_t WPS = (size_t)64 * 4 * 64 * 512;
    for (int g = 0; g < 4; ++g) {
        for (int i = 0; i < 512; i += 256) {
            const int idx = t + i;
            const int kk = idx >> 4, n = idx & 15;
            ws2[kk][n] = src[(size_t)(kt * 32 + kk) * 4096 + g * 1024 + ub * 16 + n];
        }
        __syncthreads();
        const size_t base = (((size_t)ub * 4 + g) * 64 + kt) * 512;
        for (int i = 0; i < 512; i += 256) {
            const int idx = t + i;
            const int lane = idx >> 3, j = idx & 7;
            const float v = ws2[(lane >> 4) * 8 + j][lane & 15];
            const _Float16 hi = (_Float16)v;
            dst[base + idx]       = hi;
            dst[WPS + base + idx] = (_Float16)(v - (float)hi);
        }
        __syncthreads();
    }
}

// ---------------------------------------------------------------------------
// proj appendix (runs in L1-role WGs after the GEMM):
// relu(x_t @ W + b) -> frag hi/lo.  256 WGs, each a 16m x 128u tile.
// id: mrow = id & 31 (16-row block), uc = id >> 5 (128-u block).
// ---------------------------------------------------------------------------
__device__ __forceinline__ void proj_append(
    const float* __restrict__ x, const float* __restrict__ W,
    const float* __restrict__ bias, _Float16* __restrict__ pf,
    int tstep, int id, char* smem)
{
    float (*ws)[68]  = (float(*)[68])smem;              // [128][68]  34816 B
    float (*xs)[132] = (float(*)[132])(smem + 34816);   // [16][132]   8448 B
    float (*zl)[132] = (float(*)[132])(smem + 43264);   // [16][132]   8448 B

    const int t = threadIdx.x;
    const int mrow = id & 31;
    const int uc   = id >> 5;          // 0..7
    __syncthreads();                   // LDS reuse after lstm_body
    {
        const int m = t >> 4, kq = t & 15;
        const float* xr = x + (size_t)(mrow * 16 + m) * (T_STEPS * NIN)
                            + (size_t)tstep * NIN + kq * 8;
        *(float4v*)&xs[m][kq * 8]     = *(const float4v*)(xr);
        *(float4v*)&xs[m][kq * 8 + 4] = *(const float4v*)(xr + 4);
    }
    for (int h = 0; h < 2; ++h) {
        __syncthreads();
#pragma unroll
        for (int i = 0; i < 8; ++i) {
            const int idx = t + i * 256;
            const int k = idx >> 4, u4 = idx & 15;
            *(float4v*)&ws[k][u4 * 4] =
                *(const float4v*)(W + (size_t)k * NHID + uc * 128 + h * 64 + u4 * 4);
        }
        __syncthreads();
        const int m = t >> 4, u4 = t & 15;
        float4v acc = {0.f, 0.f, 0.f, 0.f};
#pragma unroll 4
        for (int k = 0; k < NIN; ++k) {
            const float a = xs[m][k];
            const float4v wv = *(const float4v*)&ws[k][u4 * 4];
#pragma unroll
            for (int c = 0; c < 4; ++c) acc[c] = fmaf(a, wv[c], acc[c]);
        }
        const float4v bv = *(const float4v*)&bias[uc * 128 + h * 64 + u4 * 4];
#pragma unroll
        for (int c = 0; c < 4; ++c)
            zl[m][h * 64 + u4 * 4 + c] = fmaxf(acc[c] + bv[c], 0.0f);
    }
    __syncthreads();
    // frag-out: wave w handles u-subtile w (32 u each)
    const int w = t >> 6, l = t & 63;
    const int m16 = l & 15, jb = (l >> 4) * 8;
    half8 hv, lv;
#pragma unroll
    for (int j = 0; j < 8; ++j) {
        const float v = zl[m16][w * 32 + jb + j];
        const _Float16 hi = (_Float16)v;
        hv[j] = hi;
        lv[j] = (_Float16)(v - (float)hi);
    }
    const size_t APS = (size_t)32 * 32 * 512;
    const size_t off = ((size_t)mrow * 32 + (uc * 4 + w)) * 512 + l * 8;
    *(half8*)(pf + off)       = hv;
    *(half8*)(pf + APS + off) = lv;
}

// ---------------------------------------------------------------------------
// LSTM task body (256 threads = 4 waves = nh x kh).  Wave: 64m x 16u x 4g,
// K-half 1024 (32 kt).  Register-double-buffered direct-from-global frags.
// ---------------------------------------------------------------------------
__device__ __forceinline__ void lstm_body(
    const _Float16* __restrict__ A0, const _Float16* __restrict__ A1,
    const _Float16* __restrict__ Wf, const float* __restrict__ bias,
    const float* __restrict__ c_old, float* __restrict__ c_new,
    _Float16* __restrict__ hout, float* __restrict__ out_f32,
    int id, char* smem)
{
    float (*red)[4096] = (float(*)[4096])smem;           // [2][4096]
    float (*hl)[36]    = (float(*)[36])(smem + 32768);   // [64][36]

    const int tid = threadIdx.x;
    const int w = tid >> 6, l = tid & 63;
    const int nh = w & 1, kh = w >> 1;
    const int xcd = id & 7;
    const int s   = id >> 3;
    const int mgrp = s & 7;
    const int wgu  = xcd * 4 + (s >> 3);
    const int ub   = wgu * 2 + nh;
    const int q = l >> 4, n = l & 15;

    const _Float16* Af = kh ? A1 : A0;
    const size_t APS = (size_t)32 * 32 * 512;
    const size_t WPS = (size_t)64 * 4 * 64 * 512;

    const char* aB[2][4];
    const char* bB[2][4];
#pragma unroll
    for (int p = 0; p < 2; ++p)
#pragma unroll
        for (int mt = 0; mt < 4; ++mt)
            aB[p][mt] = (const char*)(Af + p * APS + (size_t)(mgrp * 4 + mt) * 32 * 512);
#pragma unroll
    for (int p = 0; p < 2; ++p)
#pragma unroll
        for (int g = 0; g < 4; ++g)
            bB[p][g] = (const char*)(Wf + p * WPS + (((size_t)ub * 4 + g) * 64 + kh * 32) * 512);
    const uint32_t lo16 = (uint32_t)l * 16;

    half8 Ab[2][2][4], Bb[2][2][4];
    float4v acc[4][4];
#pragma unroll
    for (int mt = 0; mt < 4; ++mt)
#pragma unroll
        for (int g = 0; g < 4; ++g)
            acc[mt][g] = (float4v){0.f, 0.f, 0.f, 0.f};

    auto loadbuf = [&](int kt, int buf) {
        const uint32_t off = lo16 + (uint32_t)((kt < 31) ? kt : 31) * 1024u;
#pragma unroll
        for (int p = 0; p < 2; ++p)
#pragma unroll
            for (int mt = 0; mt < 4; ++mt)
                Ab[buf][p][mt] = *(const half8*)(aB[p][mt] + off);
#pragma unroll
        for (int p = 0; p < 2; ++p)
#pragma unroll
            for (int g = 0; g < 4; ++g)
                Bb[buf][p][g] = *(const half8*)(bB[p][g] + off);
    };
    auto mstep = [&](int buf) {
#pragma unroll
        for (int g = 0; g < 4; ++g)
#pragma unroll
            for (int mt = 0; mt < 4; ++mt)
                acc[mt][g] = __builtin_amdgcn_mfma_f32_16x16x32_f16(Ab[buf][0][mt], Bb[buf][0][g], acc[mt][g], 0, 0, 0);
#pragma unroll
        for (int g = 0; g < 4; ++g)
#pragma unroll
            for (int mt = 0; mt < 4; ++mt)
                acc[mt][g] = __builtin_amdgcn_mfma_f32_16x16x32_f16(Ab[buf][1][mt], Bb[buf][0][g], acc[mt][g], 0, 0, 0);
#pragma unroll
        for (int g = 0; g < 4; ++g)
#pragma unroll
            for (int mt = 0; mt < 4; ++mt)
                acc[mt][g] = __builtin_amdgcn_mfma_f32_16x16x32_f16(Ab[buf][0][mt], Bb[buf][1][g], acc[mt][g], 0, 0, 0);
    };

    loadbuf(0, 0);
    for (int kt = 0; kt < 32; kt += 2) {
        loadbuf(kt + 1, 1);
        mstep(0);
        loadbuf(kt + 2, 0);
        mstep(1);
    }

    // k-half reduction
    __syncthreads();
    if (kh == 1) {
#pragma unroll
        for (int mt = 0; mt < 4; ++mt)
#pragma unroll
            for (int g = 0; g < 4; ++g)
#pragma unroll
                for (int r = 0; r < 4; ++r)
                    red[nh][((mt * 4 + g) * 4 + r) * 64 + l] = acc[mt][g][r];
    }
    __syncthreads();
    if (kh == 0) {
#pragma unroll
        for (int mt = 0; mt < 4; ++mt)
#pragma unroll
            for (int g = 0; g < 4; ++g)
#pragma unroll
                for (int r = 0; r < 4; ++r)
                    acc[mt][g][r] += red[nh][((mt * 4 + g) * 4 + r) * 64 + l];

        const int unit = ub * 16 + n;
        const float bi = bias[unit];
        const float bj = bias[NHID + unit];
        const float bf = bias[2 * NHID + unit];
        const float bo = bias[3 * NHID + unit];
#pragma unroll
        for (int mt = 0; mt < 4; ++mt) {
            const int mtglob = mgrp * 4 + mt;
            const size_t cbase = ((size_t)mtglob * 64 + ub) * 256 + l * 4;
            const float4v cv = *(const float4v*)(c_old + cbase);
            float4v cn;
            float hn[4];
#pragma unroll
            for (int r = 0; r < 4; ++r) {
                const float zi = acc[mt][0][r] + bi;
                const float zj = acc[mt][1][r] + bj;
                const float zf = acc[mt][2][r] + bf;
                const float zo = acc[mt][3][r] + bo;
                const float c = cv[r] * sigmoid_f(zf + 1.0f) + sigmoid_f(zi) * tanh_f(zj);
                cn[r] = c;
                hn[r] = tanh_f(c) * sigmoid_f(zo);
            }
            *(float4v*)(c_new + cbase) = cn;
#pragma unroll
            for (int r = 0; r < 4; ++r)
                hl[mt * 16 + q * 4 + r][nh * 16 + n] = hn[r];
            if (out_f32) {
#pragma unroll
                for (int r = 0; r < 4; ++r)
                    out_f32[(size_t)(mgrp * 64 + mt * 16 + q * 4 + r) * NHID + unit] = hn[r];
            }
        }
    }
    __syncthreads();
    // frag-out of new h: wave w handles m-tile w
    const int mloc = w * 16 + n;
    const int q8 = q * 8;
    const float4v v0 = *(const float4v*)&hl[mloc][q8];
    const float4v v1 = *(const float4v*)&hl[mloc][q8 + 4];
    half8 hv, lv;
#pragma unroll
    for (int jx = 0; jx < 4; ++jx) {
        _Float16 h0 = (_Float16)v0[jx];
        _Float16 h1 = (_Float16)v1[jx];
        hv[jx]     = h0;  hv[jx + 4] = h1;
        lv[jx]     = (_Float16)(v0[jx] - (float)h0);
        lv[jx + 4] = (_Float16)(v1[jx] - (float)h1);
    }
    const size_t off = (((size_t)(mgrp * 4 + w)) * 32 + wgu) * 512 + l * 8;
    *(half8*)(hout + off)       = hv;
    *(half8*)(hout + APS + off) = lv;
}

// ---------------------------------------------------------------------------
// One phase, grid 512 (exactly 2 WGs/CU):
//   bid 0..255   : L1(t1) GEMM, then proj(tp) appendix
//   bid 256..511 : L2(t2) GEMM
// ---------------------------------------------------------------------------
__global__ __launch_bounds__(256, 2)
void phase_kernel(const float* __restrict__ x, const float* __restrict__ W_h,
                  const float* __restrict__ b_h,
                  const _Float16* __restrict__ pf_in, _Float16* __restrict__ pf_out,
                  const _Float16* __restrict__ wf1, const float* __restrict__ b1,
                  const float* __restrict__ c1_in, float* __restrict__ c1_out,
                  const _Float16* __restrict__ h1_in, _Float16* __restrict__ h1_out,
                  const _Float16* __restrict__ wf2, const float* __restrict__ b2,
                  const float* __restrict__ c2_in, float* __restrict__ c2_out,
                  const _Float16* __restrict__ h2_in, _Float16* __restrict__ h2_out,
                  float* __restrict__ out_f32, int t1, int t2, int tp)
{
    __shared__ __align__(16) char smem[62464];
    const int bid = blockIdx.x;
    if (bid < 256) {
        if (t1 >= 0 && t1 <= 255)
            lstm_body(pf_in, h1_in, wf1, b1, c1_in, c1_out,
                      h1_out, nullptr, bid, smem);
        if (tp >= 0 && tp <= 255)
            proj_append(x, W_h, b_h, pf_out, tp, bid, smem);
    } else {
        if (t2 >= 0 && t2 <= 255)
            lstm_body(h1_in, h2_in, wf2, b2, c2_in, c2_out,
                      h2_out, out_f32, bid - 256, smem);
    }
}

// ---------------------------------------------------------------------------
extern "C" void kernel_launch(void* const* d_in, const int* in_sizes, int n_in,
                              void* d_out, int out_size, void* d_ws, size_t ws_size,
                              hipStream_t stream)
{
    const float* x   = (const float*)d_in[0];
    const float* W_h = (const float*)d_in[1];
    const float* b_h = (const float*)d_in[2];
    const float* k1  = (const float*)d_in[3];
    const float* b1  = (const float*)d_in[4];
    const float* k2  = (const float*)d_in[5];
    const float* b2  = (const float*)d_in[6];
    float* out = (float*)d_out;

    const size_t MB = 1024 * 1024;
    uint8_t* wsb = (uint8_t*)d_ws;
    // Zero block (first 8 MB) = exactly the buffers read before first write:
    //   c1f[0], h1f[0]  (first L1 at phase 0, pi=0)
    //   c2f[1], h2f[1]  (first L2 at phase 1, pi=1)
    float*    c1f[2] = {(float*)(wsb + 0 * MB),    (float*)(wsb + 8 * MB)};
    _Float16* h1f[2] = {(_Float16*)(wsb + 2 * MB), (_Float16*)(wsb + 10 * MB)};
    float*    c2f[2] = {(float*)(wsb + 12 * MB),   (float*)(wsb + 4 * MB)};
    _Float16* h2f[2] = {(_Float16*)(wsb + 14 * MB),(_Float16*)(wsb + 6 * MB)};
    _Float16* pf[2]  = {(_Float16*)(wsb + 16 * MB), (_Float16*)(wsb + 18 * MB)};
    _Float16* wf1 = (_Float16*)(wsb + 20 * MB);
    _Float16* wf2 = (_Float16*)(wsb + 52 * MB);   // ends at 84 MB

    hipMemsetAsync(d_ws, 0, 8 * MB, stream);
    convert_weights<<<dim3(64, 64, 2), 256, 0, stream>>>(k1, k2, wf1, wf2);

    // pre-dispatch: proj(0) only (GEMMs disabled via t1=t2=-1)
    phase_kernel<<<512, 256, 0, stream>>>(x, W_h, b_h,
        pf[0], pf[0], wf1, b1, c1f[0], c1f[1], h1f[0], h1f[1],
        wf2, b2, c2f[0], c2f[1], h2f[0], h2f[1], nullptr, -1, -1, 0);

    for (int p = 0; p <= 256; ++p) {
        const int pi = p & 1, po = pi ^ 1;
        phase_kernel<<<512, 256, 0, stream>>>(x, W_h, b_h,
            pf[pi], pf[po],
            wf1, b1, c1f[pi], c1f[po], h1f[pi], h1f[po],
            wf2, b2, c2f[pi], c2f[po], h2f[pi], h2f[po],
            (p == 256) ? out : nullptr, p, p - 1, p + 1);
    }
}